// Round 1
// baseline (266.555 us; speedup 1.0000x reference)
//
#include <hip/hip_runtime.h>

// Cost volume: out[b,d,h,w] = (w>=d) ? (1/32) * sum_c L[b,c,h,w]*R[b,c,h,w-d] : 0
// B=4, C=32, H=256, W=512, D=64, fp32 (no MFMA: CDNA4 has no fp32-input MFMA,
// and exact fp32 match vs reference rules out bf16).
//
// v2 strategy (occupancy round): previous kernel was latency-bound
// (VALUBusy 22%, HBM 27%, Occ 32%) because 72 KB LDS capped residency at
// 2 blocks/CU (16 waves). Changes:
//   1. Channel-chunked staging (16 ch/chunk -> 36 KB LDS -> 4 blocks/CU).
//   2. d-range split across 2 blocks (DT 16->8): acc 64->32 floats, live
//      regs ~60 -> __launch_bounds__(512,8) => 8 waves/SIMD, 32 waves/CU.
//   3. global_load_lds width=16 for R staging (no VGPR round-trip; lane
//      pattern is contiguous 16B, channel rows align to wave boundaries).
// Per c-iter per thread: 1 global dwordx4 (L) + 3 ds_read_b128 (12-float
// R window) + 32 v_fma_f32.

constexpr int Bn = 4, Cn = 32, Hn = 256, Wn = 512, Dn = 64;
constexpr int CCH = 16;            // channels per LDS chunk
constexpr int WT = 4, DT = 8;      // per-thread output tile
constexpr int PAD = 64;            // zero pad -> automatic w<d masking
constexpr int STRIDE = PAD + Wn;   // 576 floats per channel in LDS
constexpr int HW = Hn * Wn;        // 131072

__global__ __launch_bounds__(512, 8)
void cost_volume_kernel(const float* __restrict__ left,
                        const float* __restrict__ right,
                        float* __restrict__ out)
{
    __shared__ __align__(16) float Rs[CCH * STRIDE];   // 36,864 B

    const int tid  = threadIdx.x;
    const int bid  = blockIdx.x;
    const int dblk = bid & 1;          // which 32-wide d half
    const int bh   = bid >> 1;
    const int b    = bh >> 8;          // H = 256
    const int h    = bh & (Hn - 1);

    const float* Lrow = left  + (b * Cn * Hn + h) * Wn;   // channel stride = HW
    const float* Rrow = right + (b * Cn * Hn + h) * Wn;

    // --- zero the left pad once: 16 channels x 64 floats = 256 float4
    if (tid < CCH * (PAD / 4)) {
        const int c  = tid >> 4;            // 0..15
        const int wq = (tid & 15) << 2;     // 0..60
        *reinterpret_cast<float4*>(&Rs[c * STRIDE + wq]) =
            make_float4(0.f, 0.f, 0.f, 0.f);
    }

    // --- thread tile: tw in [0,128) covers w, td in [0,4) covers 8 d each
    const int tw = tid & 127;
    const int td = tid >> 7;
    const int w0 = tw << 2;                       // WT=4
    const int d0 = (dblk << 5) + (td << 3);       // DT=8, absolute d base
    const int rbase = PAD + w0 - d0 - 8;          // >= 0, multiple of 4

    float acc[DT][WT];
    #pragma unroll
    for (int j = 0; j < DT; ++j)
        #pragma unroll
        for (int i = 0; i < WT; ++i)
            acc[j][i] = 0.f;

    for (int cc = 0; cc < Cn; cc += CCH) {
        if (cc) __syncthreads();   // all waves done reading previous chunk

        // stage chunk: 16 ch x 512 floats = 2048 float4, 4 per thread,
        // direct global->LDS (dest = wave-uniform base + lane*16: holds,
        // since 128 float4/channel row = 2 full waves, boundary-aligned)
        #pragma unroll
        for (int k = 0; k < 4; ++k) {
            const int f = tid + (k << 9);       // float4 index, 0..2047
            const int c = f >> 7;               // 128 float4 per channel row
            const int w = (f & 127) << 2;
            __builtin_amdgcn_global_load_lds(
                (const __attribute__((address_space(1))) void*)(Rrow + (cc + c) * HW + w),
                (__attribute__((address_space(3))) void*)(&Rs[c * STRIDE + PAD + w]),
                16, 0, 0);
        }
        __syncthreads();   // drains vmcnt before barrier

        #pragma unroll 2
        for (int c = 0; c < CCH; ++c) {
            const float4 Lv =
                *reinterpret_cast<const float4*>(&Lrow[(cc + c) * HW + w0]);

            const float* rp = &Rs[c * STRIDE + rbase];
            float r[12];                        // window R[w0-d0-8 .. w0-d0+3]
            #pragma unroll
            for (int q = 0; q < 3; ++q)
                *reinterpret_cast<float4*>(&r[q * 4]) =
                    *reinterpret_cast<const float4*>(&rp[q * 4]);

            // acc[j][i] += L[c][w0+i] * R[c][w0+i - (d0+j)] -> r[8+i-j] in [1,11]
            #pragma unroll
            for (int j = 0; j < DT; ++j) {
                acc[j][0] = fmaf(Lv.x, r[8 - j],  acc[j][0]);
                acc[j][1] = fmaf(Lv.y, r[9 - j],  acc[j][1]);
                acc[j][2] = fmaf(Lv.z, r[10 - j], acc[j][2]);
                acc[j][3] = fmaf(Lv.w, r[11 - j], acc[j][3]);
            }
        }
    }

    // --- epilogue: out[b][d0+j][h][w0..w0+3], coalesced dwordx4 per j
    constexpr float inv = 1.0f / 32.0f;
    float* op = out + ((b * Dn + d0) * Hn + h) * Wn + w0;
    #pragma unroll
    for (int j = 0; j < DT; ++j) {
        const float4 v = make_float4(acc[j][0] * inv, acc[j][1] * inv,
                                     acc[j][2] * inv, acc[j][3] * inv);
        *reinterpret_cast<float4*>(&op[j * HW]) = v;
    }
}

extern "C" void kernel_launch(void* const* d_in, const int* in_sizes, int n_in,
                              void* d_out, int out_size, void* d_ws, size_t ws_size,
                              hipStream_t stream) {
    const float* left  = (const float*)d_in[0];
    const float* right = (const float*)d_in[1];
    float* out = (float*)d_out;
    cost_volume_kernel<<<dim3(Bn * Hn * 2), dim3(512), 0, stream>>>(left, right, out);
}

// Round 2
// 244.946 us; speedup vs baseline: 1.0882x; 1.0882x over previous
//
#include <hip/hip_runtime.h>

// Cost volume: out[b,d,h,w] = (w>=d) ? (1/32) * sum_c L[b,c,h,w]*R[b,c,h,w-d] : 0
// B=4, C=32, H=256, W=512, D=64, fp32 (no fp32-input MFMA on CDNA4; exact
// fp32 match vs reference rules out bf16).
//
// v3 (latency-chain round): v1 (16 waves/CU) and v2 (23 waves/CU) both pinned
// at VALUBusy 22% -> bottleneck is the per-channel global L load on the FMA
// dependency chain, NOT occupancy. Fix: stage BOTH L and R via
// global_load_lds (fire-and-forget), double-buffered chunks of 8 channels so
// chunk k+1 staging overlaps chunk k compute. Inner loop is pure LDS+VALU.
// Also reverts v2's d-split (it doubled FETCH and +25% WRITE): one block per
// (b,h) row, DT=16 x WT=4 per thread.
//
// LDS: 2 x (R 8x576 + L 8x512) floats = 69,632 B -> 2 blocks/CU (fine: v2
// proved more waves don't help; what matters is the short inner chain).

constexpr int Bn = 4, Cn = 32, Hn = 256, Wn = 512, Dn = 64;
constexpr int CCH = 8;             // channels per LDS chunk
constexpr int WT = 4, DT = 16;     // per-thread output tile
constexpr int PAD = 64;            // zero pad -> automatic w<d masking
constexpr int STRIDE = PAD + Wn;   // 576 floats per R channel row in LDS
constexpr int HW = Hn * Wn;        // 131072
constexpr int RBUF = CCH * STRIDE; // 4608 floats
constexpr int LBUF = CCH * Wn;     // 4096 floats

__global__ __launch_bounds__(512, 4)
void cost_volume_kernel(const float* __restrict__ left,
                        const float* __restrict__ right,
                        float* __restrict__ out)
{
    __shared__ __align__(16) float Rs[2][RBUF];   // 36,864 B
    __shared__ __align__(16) float Ls[2][LBUF];   // 32,768 B

    const int tid = threadIdx.x;
    const int bh  = blockIdx.x;
    const int b   = bh >> 8;          // H = 256
    const int h   = bh & (Hn - 1);

    const float* Lrow = left  + (b * Cn * Hn + h) * Wn;   // channel stride = HW
    const float* Rrow = right + (b * Cn * Hn + h) * Wn;

    // --- zero the left pads of both R buffers once: 2 x 8ch x 64 floats
    if (tid < 2 * CCH * (PAD / 4)) {            // 256 threads, 1 float4 each
        const int s  = tid >> 7;                // buffer
        const int c  = (tid >> 4) & (CCH - 1);
        const int wq = (tid & 15) << 2;
        *reinterpret_cast<float4*>(&Rs[s][c * STRIDE + wq]) =
            make_float4(0.f, 0.f, 0.f, 0.f);
    }

    // --- staging: 8 ch x 512 floats each of L and R = 1024 float4 each,
    // 2 global_load_lds per array per thread. Wave-uniform LDS base +
    // lane*16 holds: 128 float4/channel row, waves never straddle rows.
    auto stage = [&](int sel, int cc) {
        #pragma unroll
        for (int k = 0; k < 2; ++k) {
            const int f = tid + (k << 9);       // float4 index, 0..1023
            const int c = f >> 7;               // 128 float4 per channel row
            const int w = (f & 127) << 2;
            __builtin_amdgcn_global_load_lds(
                (const __attribute__((address_space(1))) void*)(Rrow + (cc + c) * HW + w),
                (__attribute__((address_space(3))) void*)(&Rs[sel][c * STRIDE + PAD + w]),
                16, 0, 0);
            __builtin_amdgcn_global_load_lds(
                (const __attribute__((address_space(1))) void*)(Lrow + (cc + c) * HW + w),
                (__attribute__((address_space(3))) void*)(&Ls[sel][c * Wn + w]),
                16, 0, 0);
        }
    };

    // --- thread tile: tw in [0,128) covers w, td in [0,4) covers d
    const int tw = tid & 127;
    const int td = tid >> 7;
    const int w0 = tw << 2;                 // WT=4
    const int d0 = td << 4;                 // DT=16
    const int rbase = PAD + w0 - d0 - 16;   // >= 0, multiple of 4

    float acc[DT][WT];
    #pragma unroll
    for (int j = 0; j < DT; ++j)
        #pragma unroll
        for (int i = 0; i < WT; ++i)
            acc[j][i] = 0.f;

    stage(0, 0);                            // prologue: chunk 0 -> buffer 0

    int sel = 0;
    for (int cc = 0; cc < Cn; cc += CCH) {
        // Drains the global_load_lds issued for buffer `sel` (one chunk ago
        // or prologue) and closes the read phase of buffer sel^1.
        __syncthreads();

        if (cc + CCH < Cn)
            stage(sel ^ 1, cc + CCH);       // fire-and-forget next chunk

        const float* Rb = &Rs[sel][0];
        const float* Lb = &Ls[sel][0];

        #pragma unroll 2
        for (int c = 0; c < CCH; ++c) {
            const float4 Lv =
                *reinterpret_cast<const float4*>(&Lb[c * Wn + w0]);

            const float* rp = &Rb[c * STRIDE + rbase];
            float r[20];                    // window R[w0-d0-16 .. w0-d0+3]
            #pragma unroll
            for (int q = 0; q < 5; ++q)
                *reinterpret_cast<float4*>(&r[q * 4]) =
                    *reinterpret_cast<const float4*>(&rp[q * 4]);

            // acc[j][i] += L[c][w0+i] * R[c][w0+i-(d0+j)] -> r[16+i-j] in [1,19]
            #pragma unroll
            for (int j = 0; j < DT; ++j) {
                acc[j][0] = fmaf(Lv.x, r[16 - j], acc[j][0]);
                acc[j][1] = fmaf(Lv.y, r[17 - j], acc[j][1]);
                acc[j][2] = fmaf(Lv.z, r[18 - j], acc[j][2]);
                acc[j][3] = fmaf(Lv.w, r[19 - j], acc[j][3]);
            }
        }
        sel ^= 1;
    }

    // --- epilogue: out[b][d0+j][h][w0..w0+3], coalesced dwordx4 per j
    constexpr float inv = 1.0f / 32.0f;
    float* op = out + ((b * Dn + d0) * Hn + h) * Wn + w0;
    #pragma unroll
    for (int j = 0; j < DT; ++j) {
        const float4 v = make_float4(acc[j][0] * inv, acc[j][1] * inv,
                                     acc[j][2] * inv, acc[j][3] * inv);
        *reinterpret_cast<float4*>(&op[j * HW]) = v;
    }
}

extern "C" void kernel_launch(void* const* d_in, const int* in_sizes, int n_in,
                              void* d_out, int out_size, void* d_ws, size_t ws_size,
                              hipStream_t stream) {
    const float* left  = (const float*)d_in[0];
    const float* right = (const float*)d_in[1];
    float* out = (float*)d_out;
    cost_volume_kernel<<<dim3(Bn * Hn), dim3(512), 0, stream>>>(left, right, out);
}